// Round 13
// baseline (210.625 us; speedup 1.0000x reference)
//
#include <hip/hip_runtime.h>
#include <math.h>

#define SEQ 2048
#define DIM 1024
#define HD  128
#define NB  8
#define M_TOT (NB * SEQ)   // 16384

typedef __attribute__((ext_vector_type(8))) short   short8;   // 8 x bf16 (4 VGPRs)
typedef __attribute__((ext_vector_type(4))) short   short4v;  // 4 x bf16
typedef __attribute__((ext_vector_type(4))) float   floatx4;  // MFMA acc

__device__ __forceinline__ unsigned short f2bf(float f) {
    unsigned u = __builtin_bit_cast(unsigned, f);
    u += 0x7FFFu + ((u >> 16) & 1u);
    return (unsigned short)(u >> 16);
}
__device__ __forceinline__ float bf2f(unsigned short h) {
    unsigned u = ((unsigned)h) << 16;
    return __builtin_bit_cast(float, u);
}
__device__ __forceinline__ void async16(const void* g, void* l) {
    __builtin_amdgcn_global_load_lds(
        (const __attribute__((address_space(1))) unsigned int*)g,
        (__attribute__((address_space(3))) unsigned int*)l, 16, 0, 0);
}

#define MFMA16(a, b, c) __builtin_amdgcn_mfma_f32_16x16x32_bf16((a), (b), (c), 0, 0, 0)

// ---------------------------------------------------------------------------
// Kernel 0: W -> Wt (transposed, bf16 hi/lo split).  Wt[mat][n=128][k=1024]
// ---------------------------------------------------------------------------
__global__ __launch_bounds__(256) void wt_prep(
    const float* __restrict__ Wq, const float* __restrict__ Wk, const float* __restrict__ Wv,
    unsigned short* __restrict__ Wth, unsigned short* __restrict__ Wtl)
{
    int idx = blockIdx.x * 256 + threadIdx.x;       // [mat][n][k] flat
    int k   = idx & 1023;
    int n   = (idx >> 10) & 127;
    int mat = idx >> 17;
    const float* W = (mat == 0) ? Wq : (mat == 1) ? Wk : Wv;
    float v = W[k * HD + n];
    unsigned short hi = f2bf(v);
    Wth[idx] = hi;
    Wtl[idx] = f2bf(v - bf2f(hi));
}

// ---------------------------------------------------------------------------
// Kernel 1: FUSED QKV projection, v4 (unchanged — 2 blocks/CU N-split,
// proven in round 4).
// ---------------------------------------------------------------------------
__global__ __launch_bounds__(512, 4) void qkv_fused(
    const float* __restrict__ x,
    const unsigned short* __restrict__ Wth, const unsigned short* __restrict__ Wtl,
    const float* __restrict__ bq, const float* __restrict__ bk, const float* __restrict__ bv,
    unsigned short* __restrict__ Qh, unsigned short* __restrict__ Ql,
    unsigned short* __restrict__ Kh, unsigned short* __restrict__ Kl,
    unsigned short* __restrict__ Vt)
{
    __shared__ short lds[56 * 512];                 // 56 KB

    const int t    = threadIdx.x;
    const int lane = t & 63;
    const int w    = t >> 6;                        // 0..7
    const int lrow = lane & 15;
    const int quad = lane >> 4;

    const int R0 = blockIdx.x * 64;
    const int z  = blockIdx.y;                      // N-split half
    const int mh = w & 1;                           // row half
    const int nh = w >> 1;                          // local col frag 0..3

    // ---- B staging: 20 frags (12 hi + 8 lo); waves 0..3 take 3, 4..7 take 2
    auto stageB = [&](int k0, int qb) {
        #pragma unroll
        for (int i = 0; i < 3; ++i) {
            int f = i * 8 + w;
            if (f < 20) {
                int p   = (f >= 12);
                int ff  = p ? (f - 12) : f;
                int mat = ff >> 2, nfl = ff & 3;
                const unsigned short* src = (p ? Wtl : Wth) + (size_t)mat * (HD * DIM)
                    + (size_t)((z * 4 + nfl) * 16 + lrow) * DIM + k0 + quad * 8;
                async16(src, &lds[(qb * 28 + 8 + f) * 512 + lane * 8]);
            }
        }
    };

    // ---- A staging: thread t owns 4 floats at (row=t>>3, kk=(t&7)*4) ----
    const int arow = t >> 3;                        // 0..63
    const int akk  = (t & 7) * 4;                   // 0,4,..,28
    auto xload = [&](int k0) -> float4 {
        return *(const float4*)&x[(size_t)(R0 + arow) * DIM + k0 + akk];
    };
    auto stageA = [&](float4 xv, int qb) {
        float xf[4] = {xv.x, xv.y, xv.z, xv.w};
        short4v hv, lv;
        #pragma unroll
        for (int j = 0; j < 4; ++j) {
            unsigned short h = f2bf(xf[j]);
            hv[j] = (short)h;
            lv[j] = (short)f2bf(xf[j] - bf2f(h));
        }
        int mi = arow >> 4, lr = arow & 15, qd = akk >> 3, el = akk & 7;
        int base = (qb * 28 + mi * 2) * 512 + (qd * 16 + lr) * 8 + el;
        *(short4v*)&lds[base]       = hv;           // p=0 (hi)
        *(short4v*)&lds[base + 512] = lv;           // p=1 (lo)
    };

    floatx4 acc[2][3];                              // [mi2][Q,K,V]
    const floatx4 zf = {0.f, 0.f, 0.f, 0.f};
    #pragma unroll
    for (int mi2 = 0; mi2 < 2; ++mi2)
        #pragma unroll
        for (int c = 0; c < 3; ++c) acc[mi2][c] = zf;

    // ---- compute on buffer qb (9 ds_read_b128 + 14 MFMA per wave) ----
    auto compute = [&](int qb) {
        short8 a[2][2];                             // [mi2][hi/lo]
        #pragma unroll
        for (int mi2 = 0; mi2 < 2; ++mi2)
            #pragma unroll
            for (int p = 0; p < 2; ++p)
                a[mi2][p] = *(short8*)&lds[(qb * 28 + (mh * 2 + mi2) * 2 + p) * 512 + lane * 8];

        short8 bhq = *(short8*)&lds[(qb * 28 + 8 +  0 + nh) * 512 + lane * 8];
        short8 bhk = *(short8*)&lds[(qb * 28 + 8 +  4 + nh) * 512 + lane * 8];
        short8 bhv = *(short8*)&lds[(qb * 28 + 8 +  8 + nh) * 512 + lane * 8];
        short8 blq = *(short8*)&lds[(qb * 28 + 20 + 0 + nh) * 512 + lane * 8];
        short8 blk = *(short8*)&lds[(qb * 28 + 20 + 4 + nh) * 512 + lane * 8];

        #pragma unroll
        for (int mi2 = 0; mi2 < 2; ++mi2) {
            acc[mi2][0] = MFMA16(a[mi2][0], bhq, acc[mi2][0]);   // ah*bh
            acc[mi2][1] = MFMA16(a[mi2][0], bhk, acc[mi2][1]);
            acc[mi2][2] = MFMA16(a[mi2][0], bhv, acc[mi2][2]);   // V: hi*hi only
            acc[mi2][0] = MFMA16(a[mi2][1], bhq, acc[mi2][0]);   // al*bh
            acc[mi2][1] = MFMA16(a[mi2][1], bhk, acc[mi2][1]);
            acc[mi2][0] = MFMA16(a[mi2][0], blq, acc[mi2][0]);   // ah*bl
            acc[mi2][1] = MFMA16(a[mi2][0], blk, acc[mi2][1]);
        }
    };

    // ---- prologue: buf0 staged; x prefetched 2 deep ----
    stageB(0, 0);
    stageA(xload(0), 0);                            // one-time cold stall
    float4 xn0 = xload(32);                         // consumed at it=0
    float4 xn1 = xload(64);                         // consumed at it=1

    for (int it = 0; it < 32; ++it) {
        __syncthreads();                            // buf[it&1] staged; prev reads done
        const int k0 = it * 32;
        const int q  = it & 1;

        if (it < 31) {
            stageB(k0 + 32, q ^ 1);                 // async -> other buf
            stageA(xn0, q ^ 1);                     // x loaded 2 iters ago
            xn0 = xn1;
            int kx = (k0 + 96 <= DIM - 32) ? (k0 + 96) : (DIM - 32);
            xn1 = xload(kx);                        // 2-ahead prefetch (clamped)
        }

        compute(q);
    }

    // ---- epilogue (same numerics/mapping; cols offset by z*64) ----
    const int col = (z * 4 + nh) * 16 + lrow;
    const float bqv = bq[col], bkv = bk[col], bvv = bv[col];
    #pragma unroll
    for (int mi2 = 0; mi2 < 2; ++mi2) {
        #pragma unroll
        for (int reg = 0; reg < 4; ++reg) {
            int gm = R0 + (mh * 2 + mi2) * 16 + quad * 4 + reg;
            float vq = (acc[mi2][0][reg] + bqv) * 32.0f;         // fold sqrt(D)
            unsigned short h = f2bf(vq);
            Qh[(size_t)gm * HD + col] = h;
            Ql[(size_t)gm * HD + col] = f2bf(vq - bf2f(h));
            float vk = acc[mi2][1][reg] + bkv;
            h = f2bf(vk);
            Kh[(size_t)gm * HD + col] = h;
            Kl[(size_t)gm * HD + col] = f2bf(vk - bf2f(h));
            float vv = acc[mi2][2][reg] + bvv;
            int b = gm >> 11, s = gm & 2047;
            Vt[((size_t)b * HD + col) * SEQ + s] = f2bf(vv);
        }
    }
}

// ---------------------------------------------------------------------------
// Kernel 2: causal flash attention, v8 = v7 (R12 passing) + ONE lever:
// QK^T accumulated into THREE independent accumulators (Sa=ah*bh, Sb=al*bh,
// Sc=ah*bl), summed once after the loop.  R12's neutral result proved the
// per-tile cost is the serial dependency chain, not VALU count — the old
// 12-deep MFMA chain on a single S is now 3 independent 4-deep chains that
// pipeline.  fp32 partial-sum reorder only (absmax margin 3x).
// ---------------------------------------------------------------------------
__global__ __launch_bounds__(512) void flash_attn(
    const unsigned short* __restrict__ Qh, const unsigned short* __restrict__ Ql,
    const unsigned short* __restrict__ Kh, const unsigned short* __restrict__ Kl,
    const unsigned short* __restrict__ Vt, float* __restrict__ out,
    float* __restrict__ Opart, float* __restrict__ ML, int split)
{
    __shared__ short lds[56 * 512];                 // 56 KB

    const int t    = threadIdx.x;
    const int lane = t & 63;
    const int w    = t >> 6;                        // 0..7
    const int lrow = lane & 15;
    const int quad = lane >> 4;

    const int idx = blockIdx.x;
    const int b   = idx & 7;
    const int h   = split ? ((idx >> 3) & 1) : 0;
    const int s64 = split ? (31 - (idx >> 4)) : (31 - (idx >> 3));
    const int T   = 2 * (s64 + 1);                  // 32-key tiles in strip
    const int Th  = s64 + 1;
    const int t0  = split ? (h ? Th : 0) : 0;
    const int t1  = split ? (h ? T : Th) : T;

    const int mh = w >> 1;                          // row quarter 0..3
    const int kh = w & 1;                           // key half
    const int R  = s64 * 64 + mh * 16;              // wave's first row (batch-local)

    const size_t kbase = (size_t)b * SEQ * HD;
    const size_t vbase = (size_t)b * HD * SEQ;

    short8 qf[4][2];
    #pragma unroll
    for (int kc = 0; kc < 4; ++kc) {
        size_t off = kbase + (size_t)(R + lrow) * HD + kc * 32 + quad * 8;
        qf[kc][0] = *(const short8*)(Qh + off);
        qf[kc][1] = *(const short8*)(Ql + off);
    }

    // ---- staging: 24 frags/buffer, 3 per wave; K id 0..15 (nt,kc,p),
    //      V id 16..23 (df).  Per-frag base pointers hoisted. ----
    const unsigned short* gsrc[3];
    int gstep[3];                                   // shorts per 32-key tile
    #pragma unroll
    for (int i = 0; i < 3; ++i) {
        int id = w * 3 + i;
        if (id < 16) {
            int nt = id >> 3, kc = (id >> 1) & 3, p = id & 1;
            gsrc[i] = (p ? Kl : Kh) + kbase
                + (size_t)(nt * 16 + lrow) * HD + kc * 32 + quad * 8;
            gstep[i] = 32 * HD;
        } else {
            int df = id - 16;
            gsrc[i] = Vt + vbase + (size_t)(df * 16 + lrow) * SEQ + quad * 8;
            gstep[i] = 32;
        }
    }
    auto stage = [&](int it, int qb) {
        #pragma unroll
        for (int i = 0; i < 3; ++i) {
            int id = w * 3 + i;
            async16(gsrc[i] + (size_t)it * gstep[i],
                    &lds[(qb * 24 + id) * 512 + lane * 8]);
        }
    };

    const floatx4 zf = {0.f, 0.f, 0.f, 0.f};
    floatx4 accO[8];
    #pragma unroll
    for (int i = 0; i < 8; ++i) accO[i] = zf;
    float m_[4] = {-1e30f, -1e30f, -1e30f, -1e30f};
    float sl[4] = {0.f, 0.f, 0.f, 0.f};             // per-lane partial l

    // zero own P frag once (complement k-slots stay zero forever)
    {
        short8 z8 = {0, 0, 0, 0, 0, 0, 0, 0};
        *(short8*)&lds[(48 + w) * 512 + lane * 8] = z8;
    }
    // P-pack addresses: invariant per reg
    int paddr[4];
    {
        int kloc = kh * 16 + lrow;                  // tile-local key 0..31
        int jj = kloc & 7, q2 = (kloc >> 3) & 3;
        #pragma unroll
        for (int reg = 0; reg < 4; ++reg) {
            int lane2 = (quad * 4 + reg) + (q2 << 4);
            paddr[reg] = (48 + w) * 512 + lane2 * 8 + jj;
        }
    }

    stage(t0, 0);                                   // prologue (cold drain once)

    for (int it = t0; it < t1; ++it) {
        const int q = (it - t0) & 1;
        __syncthreads();                            // buf q staged (issued last iter)
        if (it + 1 < t1) stage(it + 1, q ^ 1);      // async -> other buf
        const int j0 = it * 32;

        // QK^T over my 16-key slice (bf16x3) — 3 independent 4-deep chains
        floatx4 Sa = zf, Sb = zf, Sc = zf;
        #pragma unroll
        for (int kc = 0; kc < 4; ++kc) {
            short8 khf = *(short8*)&lds[(q * 24 + kh * 8 + kc * 2 + 0) * 512 + lane * 8];
            short8 klf = *(short8*)&lds[(q * 24 + kh * 8 + kc * 2 + 1) * 512 + lane * 8];
            Sa = MFMA16(qf[kc][0], khf, Sa);
            Sb = MFMA16(qf[kc][0], klf, Sb);
            Sc = MFMA16(qf[kc][1], khf, Sc);
        }
        floatx4 S;
        #pragma unroll
        for (int reg = 0; reg < 4; ++reg)
            S[reg] = Sa[reg] + (Sb[reg] + Sc[reg]);
        // causal mask (wave-uniform trigger)
        if (j0 + kh * 16 + 15 > R) {
            int key = j0 + kh * 16 + lrow;
            #pragma unroll
            for (int reg = 0; reg < 4; ++reg)
                if (key > R + quad * 4 + reg) S[reg] = -INFINITY;
        }
        // defer-max (T13): per-lane check; __all(lane<=thr) == (row max<=thr)
        bool ok = (S[0] <= m_[0] + 8.0f) & (S[1] <= m_[1] + 8.0f)
                & (S[2] <= m_[2] + 8.0f) & (S[3] <= m_[3] + 8.0f);
        if (__all(ok)) {                            // common path: no cross-lane ops
            #pragma unroll
            for (int reg = 0; reg < 4; ++reg) {
                float p = __expf(S[reg] - m_[reg]);
                S[reg] = p;
                sl[reg] += p;
            }
        } else {                                    // rare: full online-softmax step
            float alpha[4];
            #pragma unroll
            for (int reg = 0; reg < 4; ++reg) {
                float m = S[reg];
                #pragma unroll
                for (int hh = 1; hh < 16; hh <<= 1) m = fmaxf(m, __shfl_xor(m, hh));
                float mnew = fmaxf(m_[reg], m);
                alpha[reg] = __expf(m_[reg] - mnew);
                m_[reg] = mnew;
                float p = __expf(S[reg] - mnew);
                S[reg] = p;
                sl[reg] = sl[reg] * alpha[reg] + p;
            }
            #pragma unroll
            for (int i = 0; i < 8; ++i)
                #pragma unroll
                for (int reg = 0; reg < 4; ++reg) accO[i][reg] *= alpha[reg];
        }

        // P: C-layout -> A-layout via own LDS frag (kh slots only)
        #pragma unroll
        for (int reg = 0; reg < 4; ++reg)
            lds[paddr[reg]] = (short)f2bf(S[reg]);
        short8 pf = *(short8*)&lds[(48 + w) * 512 + lane * 8];
        #pragma unroll
        for (int df = 0; df < 8; ++df) {
            short8 vf = *(short8*)&lds[(q * 24 + 16 + df) * 512 + lane * 8];
            accO[df] = MFMA16(pf, vf, accO[df]);
        }
    }

    // ---- deferred l reduction (once per strip) ----
    float l_[4];
    #pragma unroll
    for (int reg = 0; reg < 4; ++reg) {
        float ls = sl[reg];
        #pragma unroll
        for (int hh = 1; hh < 16; hh <<= 1) ls += __shfl_xor(ls, hh);
        l_[reg] = ls;
    }

    // ---- merge the two key-halves (once per block) ----
    __syncthreads();
    float* fl   = (float*)lds;
    float* Obuf = fl;                               // [64][128] = 32 KB
    float* mlb  = fl + 8192;                        // [kh][mh][row][2] = 256 f32
    if (lrow == 0) {
        #pragma unroll
        for (int reg = 0; reg < 4; ++reg) {
            int row = quad * 4 + reg;
            mlb[((kh * 4 + mh) * 16 + row) * 2 + 0] = m_[reg];
            mlb[((kh * 4 + mh) * 16 + row) * 2 + 1] = l_[reg];
        }
    }
    __syncthreads();
    float myw[4], Mrow[4], Drow[4];
    #pragma unroll
    for (int reg = 0; reg < 4; ++reg) {
        int row = quad * 4 + reg;
        float mo  = mlb[(((1 - kh) * 4 + mh) * 16 + row) * 2 + 0];
        float lo_ = mlb[(((1 - kh) * 4 + mh) * 16 + row) * 2 + 1];
        float M = fmaxf(m_[reg], mo);
        float d = l_[reg] * __expf(m_[reg] - M) + lo_ * __expf(mo - M);
        Mrow[reg] = M; Drow[reg] = d;
        myw[reg] = split ? __expf(m_[reg] - M) : (__expf(m_[reg] - M) / d);
    }
    if (kh == 0) {
        #pragma unroll
        for (int df = 0; df < 8; ++df)
            #pragma unroll
            for (int reg = 0; reg < 4; ++reg)
                Obuf[(mh * 16 + quad * 4 + reg) * 128 + df * 16 + lrow] =
                    accO[df][reg] * myw[reg];
    }
    __syncthreads();
    if (kh == 1) {
        if (split) {
            float* op = Opart + (size_t)idx * 8192;
            #pragma unroll
            for (int df = 0; df < 8; ++df) {
                #pragma unroll
                for (int reg = 0; reg < 4; ++reg) {
                    int row = mh * 16 + quad * 4 + reg;
                    op[row * 128 + df * 16 + lrow] =
                        Obuf[row * 128 + df * 16 + lrow] + accO[df][reg] * myw[reg];
                }
            }
            if (lrow == 0) {
                #pragma unroll
                for (int reg = 0; reg < 4; ++reg) {
                    int row = mh * 16 + quad * 4 + reg;
                    ML[(idx * 64 + row) * 2 + 0] = Mrow[reg];
                    ML[(idx * 64 + row) * 2 + 1] = Drow[reg];
                }
            }
        } else {
            #pragma unroll
            for (int df = 0; df < 8; ++df) {
                #pragma unroll
                for (int reg = 0; reg < 4; ++reg) {
                    float v = Obuf[(mh * 16 + quad * 4 + reg) * 128 + df * 16 + lrow]
                            + accO[df][reg] * myw[reg];
                    size_t o = ((size_t)(b * SEQ + R + quad * 4 + reg)) * HD + df * 16 + lrow;
                    out[o] = v;
                }
            }
        }
    }
}

// ---------------------------------------------------------------------------
// Kernel 3: split-K merge (64-row blocks).  One float4/thread; 524288 thr.
// ---------------------------------------------------------------------------
__global__ __launch_bounds__(256) void splitk_merge(
    const float* __restrict__ Opart, const float* __restrict__ ML,
    float* __restrict__ out)
{
    int tid = blockIdx.x * 256 + threadIdx.x;
    int row = tid >> 5, c4 = tid & 31;
    int b = row >> 11, r = row & 2047, s64 = r >> 6, rr = r & 63;
    int i0 = ((31 - s64) << 4) + b;                 // h=0 block
    int i1 = i0 + 8;                                // h=1 block
    float m0 = ML[(i0 * 64 + rr) * 2], l0 = ML[(i0 * 64 + rr) * 2 + 1];
    float m1 = ML[(i1 * 64 + rr) * 2], l1 = ML[(i1 * 64 + rr) * 2 + 1];
    float M  = fmaxf(m0, m1);
    float w0 = __expf(m0 - M), w1 = __expf(m1 - M);
    float inv = 1.0f / (w0 * l0 + w1 * l1);
    float4 a  = *(const float4*)&Opart[((size_t)i0 * 64 + rr) * 128 + c4 * 4];
    float4 bb = *(const float4*)&Opart[((size_t)i1 * 64 + rr) * 128 + c4 * 4];
    float4 o;
    o.x = (w0 * a.x + w1 * bb.x) * inv;
    o.y = (w0 * a.y + w1 * bb.y) * inv;
    o.z = (w0 * a.z + w1 * bb.z) * inv;
    o.w = (w0 * a.w + w1 * bb.w) * inv;
    *(float4*)&out[(size_t)row * 128 + c4 * 4] = o;
}

// ---------------------------------------------------------------------------
extern "C" void kernel_launch(void* const* d_in, const int* in_sizes, int n_in,
                              void* d_out, int out_size, void* d_ws, size_t ws_size,
                              hipStream_t stream) {
    const float* x  = (const float*)d_in[0];
    const float* Wq = (const float*)d_in[1];
    const float* bq = (const float*)d_in[2];
    const float* Wk = (const float*)d_in[3];
    const float* bk = (const float*)d_in[4];
    const float* Wv = (const float*)d_in[5];
    const float* bv = (const float*)d_in[6];
    float* out = (float*)d_out;

    unsigned short* Qh  = (unsigned short*)d_ws;
    unsigned short* Ql  = Qh  + (size_t)M_TOT * HD;
    unsigned short* Kh  = Ql  + (size_t)M_TOT * HD;
    unsigned short* Kl  = Kh  + (size_t)M_TOT * HD;
    unsigned short* Vt  = Kl  + (size_t)M_TOT * HD;
    unsigned short* Wth = Vt  + (size_t)M_TOT * HD;
    unsigned short* Wtl = Wth + (size_t)3 * HD * DIM;
    float* Opart = (float*)(Wtl + (size_t)3 * HD * DIM);   // 512 x 64 x 128 f32
    float* ML    = Opart + (size_t)512 * 64 * 128;         // 512 x 64 x 2 f32

    const size_t need = 22544384ULL + 16777216ULL + 262144ULL;   // 39.6 MB
    const int split = (ws_size >= need) ? 1 : 0;

    wt_prep<<<(3 * HD * DIM) / 256, 256, 0, stream>>>(Wq, Wk, Wv, Wth, Wtl);
    qkv_fused<<<dim3(256, 2), 512, 0, stream>>>(x, Wth, Wtl, bq, bk, bv, Qh, Ql, Kh, Kl, Vt);
    flash_attn<<<split ? 512 : 256, 512, 0, stream>>>(Qh, Ql, Kh, Kl, Vt, out, Opart, ML, split);
    if (split) splitk_merge<<<2048, 256, 0, stream>>>(Opart, ML, out);
}

// Round 14
// 202.323 us; speedup vs baseline: 1.0410x; 1.0410x over previous
//
#include <hip/hip_runtime.h>
#include <math.h>

#define SEQ 2048
#define DIM 1024
#define HD  128
#define NB  8
#define M_TOT (NB * SEQ)   // 16384

typedef __attribute__((ext_vector_type(8))) short   short8;   // 8 x bf16 (4 VGPRs)
typedef __attribute__((ext_vector_type(4))) short   short4v;  // 4 x bf16
typedef __attribute__((ext_vector_type(4))) float   floatx4;  // MFMA acc

__device__ __forceinline__ unsigned short f2bf(float f) {
    unsigned u = __builtin_bit_cast(unsigned, f);
    u += 0x7FFFu + ((u >> 16) & 1u);
    return (unsigned short)(u >> 16);
}
__device__ __forceinline__ float bf2f(unsigned short h) {
    unsigned u = ((unsigned)h) << 16;
    return __builtin_bit_cast(float, u);
}
__device__ __forceinline__ void async16(const void* g, void* l) {
    __builtin_amdgcn_global_load_lds(
        (const __attribute__((address_space(1))) unsigned int*)g,
        (__attribute__((address_space(3))) unsigned int*)l, 16, 0, 0);
}

#define MFMA16(a, b, c) __builtin_amdgcn_mfma_f32_16x16x32_bf16((a), (b), (c), 0, 0, 0)

// ---------------------------------------------------------------------------
// Kernel 0: W -> Wt (transposed, bf16 hi/lo split).  Wt[mat][n=128][k=1024]
// ---------------------------------------------------------------------------
__global__ __launch_bounds__(256) void wt_prep(
    const float* __restrict__ Wq, const float* __restrict__ Wk, const float* __restrict__ Wv,
    unsigned short* __restrict__ Wth, unsigned short* __restrict__ Wtl)
{
    int idx = blockIdx.x * 256 + threadIdx.x;       // [mat][n][k] flat
    int k   = idx & 1023;
    int n   = (idx >> 10) & 127;
    int mat = idx >> 17;
    const float* W = (mat == 0) ? Wq : (mat == 1) ? Wk : Wv;
    float v = W[k * HD + n];
    unsigned short hi = f2bf(v);
    Wth[idx] = hi;
    Wtl[idx] = f2bf(v - bf2f(hi));
}

// ---------------------------------------------------------------------------
// Kernel 1: FUSED QKV projection, v5: BM=128, N-split z in 0..3 (32 cols of
// each mat per block).  Theory: v4 (BM=64,z=2) sat AT its L2-tier traffic
// ceiling (455MB @ ~7TB/s = 62us vs 67 measured).  Doubling rows per block
// halves weight traffic (327->164MB); x re-reads hit same-XCD L2 (z-siblings
// are 128 apart in dispatch, 128%8==0).  Concurrency preserved: grid
// (128,4)=512 blocks, LDS 52KB -> 2 blocks/CU, 16 waves/CU.
// Per-wave inner loop IDENTICAL to v4 (9 ds_read_b128 + 14 MFMA, bf16x3).
// 8 waves = 4 row-quarters (mh: 32 rows) x 2 col-frags (nh: 16 cols/mat).
// Frag map (buf qb, frag = 512 shorts = 1KB):
//   A:  qb*26 + mi*2 + p            (ids 0..15; mi = row/16 in 0..7)
//   B:  qb*26 + 16 + f;  hi f=mat*2+nf (0..5), lo f=6+mat*2+nf (6..9, QK)
// ---------------------------------------------------------------------------
__global__ __launch_bounds__(512, 4) void qkv_fused(
    const float* __restrict__ x,
    const unsigned short* __restrict__ Wth, const unsigned short* __restrict__ Wtl,
    const float* __restrict__ bq, const float* __restrict__ bk, const float* __restrict__ bv,
    unsigned short* __restrict__ Qh, unsigned short* __restrict__ Ql,
    unsigned short* __restrict__ Kh, unsigned short* __restrict__ Kl,
    unsigned short* __restrict__ Vt)
{
    __shared__ short lds[52 * 512];                 // 52 KB

    const int t    = threadIdx.x;
    const int lane = t & 63;
    const int w    = t >> 6;                        // 0..7
    const int lrow = lane & 15;
    const int quad = lane >> 4;

    const int R0 = blockIdx.x * 128;
    const int z  = blockIdx.y;                      // col slice 0..3
    const int mh = w >> 1;                          // row quarter 0..3
    const int nh = w & 1;                           // 16-col frag within slice

    // ---- B staging: 10 frags; waves 0,1 take 2, waves 2..7 take 1 ----
    auto stageB = [&](int k0, int qb) {
        #pragma unroll
        for (int i = 0; i < 2; ++i) {
            int f = i * 8 + w;
            if (f < 10) {
                int p   = (f >= 6);
                int ff  = p ? (f - 6) : f;
                int mat = ff >> 1, nf = ff & 1;
                const unsigned short* src = (p ? Wtl : Wth) + (size_t)mat * (HD * DIM)
                    + (size_t)(z * 32 + nf * 16 + lrow) * DIM + k0 + quad * 8;
                async16(src, &lds[(qb * 26 + 16 + f) * 512 + lane * 8]);
            }
        }
    };

    // ---- A staging: thread t owns 8 floats at (row=t>>2, kk=(t&3)*8) ----
    const int arow = t >> 2;                        // 0..127
    const int akk  = (t & 3) * 8;                   // 0,8,16,24
    auto stageA = [&](float4 va, float4 vb, int qb) {
        float xf[8] = {va.x, va.y, va.z, va.w, vb.x, vb.y, vb.z, vb.w};
        short8 hv, lv;
        #pragma unroll
        for (int j = 0; j < 8; ++j) {
            unsigned short h = f2bf(xf[j]);
            hv[j] = (short)h;
            lv[j] = (short)f2bf(xf[j] - bf2f(h));
        }
        int mi = arow >> 4, lr = arow & 15, qd = akk >> 3;   // qd 0..3
        int base = (qb * 26 + mi * 2) * 512 + (qd * 16 + lr) * 8;
        *(short8*)&lds[base]       = hv;            // p=0 (hi)
        *(short8*)&lds[base + 512] = lv;            // p=1 (lo)
    };

    const float* xrow = x + (size_t)(R0 + arow) * DIM + akk;

    floatx4 acc[2][3];                              // [mi2][Q,K,V]
    const floatx4 zf = {0.f, 0.f, 0.f, 0.f};
    #pragma unroll
    for (int mi2 = 0; mi2 < 2; ++mi2)
        #pragma unroll
        for (int c = 0; c < 3; ++c) acc[mi2][c] = zf;

    // ---- compute on buffer qb (9 ds_read_b128 + 14 MFMA per wave) ----
    auto compute = [&](int qb) {
        short8 a[2][2];                             // [mi2][hi/lo]
        #pragma unroll
        for (int mi2 = 0; mi2 < 2; ++mi2)
            #pragma unroll
            for (int p = 0; p < 2; ++p)
                a[mi2][p] = *(short8*)&lds[(qb * 26 + (mh * 2 + mi2) * 2 + p) * 512 + lane * 8];

        short8 bhq = *(short8*)&lds[(qb * 26 + 16 + 0 + nh) * 512 + lane * 8];
        short8 bhk = *(short8*)&lds[(qb * 26 + 16 + 2 + nh) * 512 + lane * 8];
        short8 bhv = *(short8*)&lds[(qb * 26 + 16 + 4 + nh) * 512 + lane * 8];
        short8 blq = *(short8*)&lds[(qb * 26 + 16 + 6 + nh) * 512 + lane * 8];
        short8 blk = *(short8*)&lds[(qb * 26 + 16 + 8 + nh) * 512 + lane * 8];

        #pragma unroll
        for (int mi2 = 0; mi2 < 2; ++mi2) {
            acc[mi2][0] = MFMA16(a[mi2][0], bhq, acc[mi2][0]);   // ah*bh
            acc[mi2][1] = MFMA16(a[mi2][0], bhk, acc[mi2][1]);
            acc[mi2][2] = MFMA16(a[mi2][0], bhv, acc[mi2][2]);   // V: hi*hi only
            acc[mi2][0] = MFMA16(a[mi2][1], bhq, acc[mi2][0]);   // al*bh
            acc[mi2][1] = MFMA16(a[mi2][1], bhk, acc[mi2][1]);
            acc[mi2][0] = MFMA16(a[mi2][0], blq, acc[mi2][0]);   // ah*bl
            acc[mi2][1] = MFMA16(a[mi2][0], blk, acc[mi2][1]);
        }
    };

    // ---- prologue: buf0 staged; x prefetched 2 deep (named regs, rule #20)
    stageB(0, 0);
    {
        float4 v0a = *(const float4*)(xrow + 0);
        float4 v0b = *(const float4*)(xrow + 4);
        stageA(v0a, v0b, 0);                        // one-time cold stall
    }
    float4 xn0a = *(const float4*)(xrow + 32);      // consumed at it=0
    float4 xn0b = *(const float4*)(xrow + 36);
    float4 xn1a = *(const float4*)(xrow + 64);      // consumed at it=1
    float4 xn1b = *(const float4*)(xrow + 68);

    for (int it = 0; it < 32; ++it) {
        __syncthreads();                            // buf[it&1] staged; prev reads done
        const int k0 = it * 32;
        const int q  = it & 1;

        if (it < 31) {
            stageB(k0 + 32, q ^ 1);                 // async -> other buf
            stageA(xn0a, xn0b, q ^ 1);              // x loaded 2 iters ago
            xn0a = xn1a; xn0b = xn1b;
            int kx = (k0 + 96 <= DIM - 32) ? (k0 + 96) : (DIM - 32);
            xn1a = *(const float4*)(xrow + kx);     // 2-ahead prefetch (clamped)
            xn1b = *(const float4*)(xrow + kx + 4);
        }

        compute(q);
    }

    // ---- epilogue (same numerics/mapping; cols offset by z*32) ----
    const int col = z * 32 + nh * 16 + lrow;
    const float bqv = bq[col], bkv = bk[col], bvv = bv[col];
    #pragma unroll
    for (int mi2 = 0; mi2 < 2; ++mi2) {
        #pragma unroll
        for (int reg = 0; reg < 4; ++reg) {
            int gm = R0 + (mh * 2 + mi2) * 16 + quad * 4 + reg;
            float vq = (acc[mi2][0][reg] + bqv) * 32.0f;         // fold sqrt(D)
            unsigned short h = f2bf(vq);
            Qh[(size_t)gm * HD + col] = h;
            Ql[(size_t)gm * HD + col] = f2bf(vq - bf2f(h));
            float vk = acc[mi2][1][reg] + bkv;
            h = f2bf(vk);
            Kh[(size_t)gm * HD + col] = h;
            Kl[(size_t)gm * HD + col] = f2bf(vk - bf2f(h));
            float vv = acc[mi2][2][reg] + bvv;
            int b = gm >> 11, s = gm & 2047;
            Vt[((size_t)b * HD + col) * SEQ + s] = f2bf(vv);
        }
    }
}

// ---------------------------------------------------------------------------
// Kernel 2: causal flash attention, v8 (frozen — R13 passing version).
// QBLK=64, KVBLK=32 dbuf async16, per-lane defer-max check, deferred-l,
// 3-accumulator QK^T.
// ---------------------------------------------------------------------------
__global__ __launch_bounds__(512) void flash_attn(
    const unsigned short* __restrict__ Qh, const unsigned short* __restrict__ Ql,
    const unsigned short* __restrict__ Kh, const unsigned short* __restrict__ Kl,
    const unsigned short* __restrict__ Vt, float* __restrict__ out,
    float* __restrict__ Opart, float* __restrict__ ML, int split)
{
    __shared__ short lds[56 * 512];                 // 56 KB

    const int t    = threadIdx.x;
    const int lane = t & 63;
    const int w    = t >> 6;                        // 0..7
    const int lrow = lane & 15;
    const int quad = lane >> 4;

    const int idx = blockIdx.x;
    const int b   = idx & 7;
    const int h   = split ? ((idx >> 3) & 1) : 0;
    const int s64 = split ? (31 - (idx >> 4)) : (31 - (idx >> 3));
    const int T   = 2 * (s64 + 1);                  // 32-key tiles in strip
    const int Th  = s64 + 1;
    const int t0  = split ? (h ? Th : 0) : 0;
    const int t1  = split ? (h ? T : Th) : T;

    const int mh = w >> 1;                          // row quarter 0..3
    const int kh = w & 1;                           // key half
    const int R  = s64 * 64 + mh * 16;              // wave's first row (batch-local)

    const size_t kbase = (size_t)b * SEQ * HD;
    const size_t vbase = (size_t)b * HD * SEQ;

    short8 qf[4][2];
    #pragma unroll
    for (int kc = 0; kc < 4; ++kc) {
        size_t off = kbase + (size_t)(R + lrow) * HD + kc * 32 + quad * 8;
        qf[kc][0] = *(const short8*)(Qh + off);
        qf[kc][1] = *(const short8*)(Ql + off);
    }

    // ---- staging: 24 frags/buffer, 3 per wave; K id 0..15 (nt,kc,p),
    //      V id 16..23 (df).  Per-frag base pointers hoisted. ----
    const unsigned short* gsrc[3];
    int gstep[3];                                   // shorts per 32-key tile
    #pragma unroll
    for (int i = 0; i < 3; ++i) {
        int id = w * 3 + i;
        if (id < 16) {
            int nt = id >> 3, kc = (id >> 1) & 3, p = id & 1;
            gsrc[i] = (p ? Kl : Kh) + kbase
                + (size_t)(nt * 16 + lrow) * HD + kc * 32 + quad * 8;
            gstep[i] = 32 * HD;
        } else {
            int df = id - 16;
            gsrc[i] = Vt + vbase + (size_t)(df * 16 + lrow) * SEQ + quad * 8;
            gstep[i] = 32;
        }
    }
    auto stage = [&](int it, int qb) {
        #pragma unroll
        for (int i = 0; i < 3; ++i) {
            int id = w * 3 + i;
            async16(gsrc[i] + (size_t)it * gstep[i],
                    &lds[(qb * 24 + id) * 512 + lane * 8]);
        }
    };

    const floatx4 zf = {0.f, 0.f, 0.f, 0.f};
    floatx4 accO[8];
    #pragma unroll
    for (int i = 0; i < 8; ++i) accO[i] = zf;
    float m_[4] = {-1e30f, -1e30f, -1e30f, -1e30f};
    float sl[4] = {0.f, 0.f, 0.f, 0.f};             // per-lane partial l

    // zero own P frag once (complement k-slots stay zero forever)
    {
        short8 z8 = {0, 0, 0, 0, 0, 0, 0, 0};
        *(short8*)&lds[(48 + w) * 512 + lane * 8] = z8;
    }
    // P-pack addresses: invariant per reg
    int paddr[4];
    {
        int kloc = kh * 16 + lrow;                  // tile-local key 0..31
        int jj = kloc & 7, q2 = (kloc >> 3) & 3;
        #pragma unroll
        for (int reg = 0; reg < 4; ++reg) {
            int lane2 = (quad * 4 + reg) + (q2 << 4);
            paddr[reg] = (48 + w) * 512 + lane2 * 8 + jj;
        }
    }

    stage(t0, 0);                                   // prologue (cold drain once)

    for (int it = t0; it < t1; ++it) {
        const int q = (it - t0) & 1;
        __syncthreads();                            // buf q staged (issued last iter)
        if (it + 1 < t1) stage(it + 1, q ^ 1);      // async -> other buf
        const int j0 = it * 32;

        // QK^T over my 16-key slice (bf16x3) — 3 independent 4-deep chains
        floatx4 Sa = zf, Sb = zf, Sc = zf;
        #pragma unroll
        for (int kc = 0; kc < 4; ++kc) {
            short8 khf = *(short8*)&lds[(q * 24 + kh * 8 + kc * 2 + 0) * 512 + lane * 8];
            short8 klf = *(short8*)&lds[(q * 24 + kh * 8 + kc * 2 + 1) * 512 + lane * 8];
            Sa = MFMA16(qf[kc][0], khf, Sa);
            Sb = MFMA16(qf[kc][0], klf, Sb);
            Sc = MFMA16(qf[kc][1], khf, Sc);
        }
        floatx4 S;
        #pragma unroll
        for (int reg = 0; reg < 4; ++reg)
            S[reg] = Sa[reg] + (Sb[reg] + Sc[reg]);
        // causal mask (wave-uniform trigger)
        if (j0 + kh * 16 + 15 > R) {
            int key = j0 + kh * 16 + lrow;
            #pragma unroll
            for (int reg = 0; reg < 4; ++reg)
                if (key > R + quad * 4 + reg) S[reg] = -INFINITY;
        }
        // defer-max (T13): per-lane check; __all(lane<=thr) == (row max<=thr)
        bool ok = (S[0] <= m_[0] + 8.0f) & (S[1] <= m_[1] + 8.0f)
                & (S[2] <= m_[2] + 8.0f) & (S[3] <= m_[3] + 8.0f);
        if (__all(ok)) {                            // common path: no cross-lane ops
            #pragma unroll
            for (int reg = 0; reg < 4; ++reg) {
                float p = __expf(S[reg] - m_[reg]);
                S[reg] = p;
                sl[reg] += p;
            }
        } else {                                    // rare: full online-softmax step
            float alpha[4];
            #pragma unroll
            for (int reg = 0; reg < 4; ++reg) {
                float m = S[reg];
                #pragma unroll
                for (int hh = 1; hh < 16; hh <<= 1) m = fmaxf(m, __shfl_xor(m, hh));
                float mnew = fmaxf(m_[reg], m);
                alpha[reg] = __expf(m_[reg] - mnew);
                m_[reg] = mnew;
                float p = __expf(S[reg] - mnew);
                S[reg] = p;
                sl[reg] = sl[reg] * alpha[reg] + p;
            }
            #pragma unroll
            for (int i = 0; i < 8; ++i)
                #pragma unroll
                for (int reg = 0; reg < 4; ++reg) accO[i][reg] *= alpha[reg];
        }

        // P: C-layout -> A-layout via own LDS frag (kh slots only)
        #pragma unroll
        for (int reg = 0; reg < 4; ++reg)
            lds[paddr[reg]] = (short)f2bf(S[reg]);
        short8 pf = *(short8*)&lds[(48 + w) * 512 + lane * 8];
        #pragma unroll
        for (int df = 0; df < 8; ++df) {
            short8 vf = *(short8*)&lds[(q * 24 + 16 + df) * 512 + lane * 8];
            accO[df] = MFMA16(pf, vf, accO[df]);
        }
    }

    // ---- deferred l reduction (once per strip) ----
    float l_[4];
    #pragma unroll
    for (int reg = 0; reg < 4; ++reg) {
        float ls = sl[reg];
        #pragma unroll
        for (int hh = 1; hh < 16; hh <<= 1) ls += __shfl_xor(ls, hh);
        l_[reg] = ls;
    }

    // ---- merge the two key-halves (once per block) ----
    __syncthreads();
    float* fl   = (float*)lds;
    float* Obuf = fl;                               // [64][128] = 32 KB
    float* mlb  = fl + 8192;                        // [kh][mh][row][2] = 256 f32
    if (lrow == 0) {
        #pragma unroll
        for (int reg = 0; reg < 4; ++reg) {
            int row = quad * 4 + reg;
            mlb[((kh * 4 + mh) * 16 + row) * 2 + 0] = m_[reg];
            mlb[((kh * 4 + mh) * 16 + row) * 2 + 1] = l_[reg];
        }
    }
    __syncthreads();
    float myw[4], Mrow[4], Drow[4];
    #pragma unroll
    for (int reg = 0; reg < 4; ++reg) {
        int row = quad * 4 + reg;
        float mo  = mlb[(((1 - kh) * 4 + mh) * 16 + row) * 2 + 0];
        float lo_ = mlb[(((1 - kh) * 4 + mh) * 16 + row) * 2 + 1];
        float M = fmaxf(m_[reg], mo);
        float d = l_[reg] * __expf(m_[reg] - M) + lo_ * __expf(mo - M);
        Mrow[reg] = M; Drow[reg] = d;
        myw[reg] = split ? __expf(m_[reg] - M) : (__expf(m_[reg] - M) / d);
    }
    if (kh == 0) {
        #pragma unroll
        for (int df = 0; df < 8; ++df)
            #pragma unroll
            for (int reg = 0; reg < 4; ++reg)
                Obuf[(mh * 16 + quad * 4 + reg) * 128 + df * 16 + lrow] =
                    accO[df][reg] * myw[reg];
    }
    __syncthreads();
    if (kh == 1) {
        if (split) {
            float* op = Opart + (size_t)idx * 8192;
            #pragma unroll
            for (int df = 0; df < 8; ++df) {
                #pragma unroll
                for (int reg = 0; reg < 4; ++reg) {
                    int row = mh * 16 + quad * 4 + reg;
                    op[row * 128 + df * 16 + lrow] =
                        Obuf[row * 128 + df * 16 + lrow] + accO[df][reg] * myw[reg];
                }
            }
            if (lrow == 0) {
                #pragma unroll
                for (int reg = 0; reg < 4; ++reg) {
                    int row = mh * 16 + quad * 4 + reg;
                    ML[(idx * 64 + row) * 2 + 0] = Mrow[reg];
                    ML[(idx * 64 + row) * 2 + 1] = Drow[reg];
                }
            }
        } else {
            #pragma unroll
            for (int df = 0; df < 8; ++df) {
                #pragma unroll
                for (int reg = 0; reg < 4; ++reg) {
                    float v = Obuf[(mh * 16 + quad * 4 + reg) * 128 + df * 16 + lrow]
                            + accO[df][reg] * myw[reg];
                    size_t o = ((size_t)(b * SEQ + R + quad * 4 + reg)) * HD + df * 16 + lrow;
                    out[o] = v;
                }
            }
        }
    }
}

// ---------------------------------------------------------------------------
// Kernel 3: split-K merge (64-row blocks).  One float4/thread; 524288 thr.
// ---------------------------------------------------------------------------
__global__ __launch_bounds__(256) void splitk_merge(
    const float* __restrict__ Opart, const float* __restrict__ ML,
    float* __restrict__ out)
{
    int tid = blockIdx.x * 256 + threadIdx.x;
    int row = tid >> 5, c4 = tid & 31;
    int b = row >> 11, r = row & 2047, s64 = r >> 6, rr = r & 63;
    int i0 = ((31 - s64) << 4) + b;                 // h=0 block
    int i1 = i0 + 8;                                // h=1 block
    float m0 = ML[(i0 * 64 + rr) * 2], l0 = ML[(i0 * 64 + rr) * 2 + 1];
    float m1 = ML[(i1 * 64 + rr) * 2], l1 = ML[(i1 * 64 + rr) * 2 + 1];
    float M  = fmaxf(m0, m1);
    float w0 = __expf(m0 - M), w1 = __expf(m1 - M);
    float inv = 1.0f / (w0 * l0 + w1 * l1);
    float4 a  = *(const float4*)&Opart[((size_t)i0 * 64 + rr) * 128 + c4 * 4];
    float4 bb = *(const float4*)&Opart[((size_t)i1 * 64 + rr) * 128 + c4 * 4];
    float4 o;
    o.x = (w0 * a.x + w1 * bb.x) * inv;
    o.y = (w0 * a.y + w1 * bb.y) * inv;
    o.z = (w0 * a.z + w1 * bb.z) * inv;
    o.w = (w0 * a.w + w1 * bb.w) * inv;
    *(float4*)&out[(size_t)row * 128 + c4 * 4] = o;
}

// ---------------------------------------------------------------------------
extern "C" void kernel_launch(void* const* d_in, const int* in_sizes, int n_in,
                              void* d_out, int out_size, void* d_ws, size_t ws_size,
                              hipStream_t stream) {
    const float* x  = (const float*)d_in[0];
    const float* Wq = (const float*)d_in[1];
    const float* bq = (const float*)d_in[2];
    const float* Wk = (const float*)d_in[3];
    const float* bk = (const float*)d_in[4];
    const float* Wv = (const float*)d_in[5];
    const float* bv = (const float*)d_in[6];
    float* out = (float*)d_out;

    unsigned short* Qh  = (unsigned short*)d_ws;
    unsigned short* Ql  = Qh  + (size_t)M_TOT * HD;
    unsigned short* Kh  = Ql  + (size_t)M_TOT * HD;
    unsigned short* Kl  = Kh  + (size_t)M_TOT * HD;
    unsigned short* Vt  = Kl  + (size_t)M_TOT * HD;
    unsigned short* Wth = Vt  + (size_t)M_TOT * HD;
    unsigned short* Wtl = Wth + (size_t)3 * HD * DIM;
    float* Opart = (float*)(Wtl + (size_t)3 * HD * DIM);   // 512 x 64 x 128 f32
    float* ML    = Opart + (size_t)512 * 64 * 128;         // 512 x 64 x 2 f32

    const size_t need = 22544384ULL + 16777216ULL + 262144ULL;   // 39.6 MB
    const int split = (ws_size >= need) ? 1 : 0;

    wt_prep<<<(3 * HD * DIM) / 256, 256, 0, stream>>>(Wq, Wk, Wv, Wth, Wtl);
    qkv_fused<<<dim3(128, 4), 512, 0, stream>>>(x, Wth, Wtl, bq, bk, bv, Qh, Ql, Kh, Kl, Vt);
    flash_attn<<<split ? 512 : 256, 512, 0, stream>>>(Qh, Ql, Kh, Kl, Vt, out, Opart, ML, split);
    if (split) splitk_merge<<<2048, 256, 0, stream>>>(Opart, ML, out);
}